// Round 5
// baseline (626.205 us; speedup 1.0000x reference)
//
#include <hip/hip_runtime.h>
#include <hip/hip_cooperative_groups.h>
#include <math.h>

namespace cg = cooperative_groups;

#define N_NODES 16000
#define E_EDGES 256000
#define DIM 128
#define HEADS 4
#define LRELU_ALPHA 0.2f
#define NBLK 512
#define NTHR 256
#define GT_STRIDE (NBLK * NTHR)

typedef unsigned short u16;
typedef unsigned int u32;
typedef short bf16x8 __attribute__((ext_vector_type(8)));
typedef float floatx4 __attribute__((ext_vector_type(4)));

#define AS1 __attribute__((address_space(1)))
#define AS3 __attribute__((address_space(3)))

__device__ __forceinline__ u16 f2bf(float f) {
    u32 u = __float_as_uint(f);
    u32 r = (u + 0x7fffu + ((u >> 16) & 1u)) >> 16;   // RNE
    return (u16)r;
}
__device__ __forceinline__ float bflo(u32 v) { return __uint_as_float(v << 16); }
__device__ __forceinline__ float bfhi(u32 v) { return __uint_as_float(v & 0xffff0000u); }
__device__ __forceinline__ float bfs(u16 v) { return __uint_as_float((u32)v << 16); }

// ---------- 128x128 bf16 MFMA TN tile: C = A(.,K) * Bt(.,K)^T, bf16 out ----------
__device__ __forceinline__ void gemm_tile(const u16* A, const u16* Bt, u16* C,
    int K, int lda, int ldb, int ldc, int row0, int col0, char* SMp, int tid)
{
    u16 (*Alds)[32] = (u16(*)[32])SMp;
    u16 (*Blds)[32] = (u16(*)[32])(SMp + 8192);
    const int wave = tid >> 6;
    const int lane = tid & 63;
    const int quad = lane >> 4;
    const int l15  = lane & 15;
    const int wm = (wave >> 1) * 64;
    const int wn = (wave & 1) * 64;
    const int ch0 = wave * 2;
    const int srow = lane >> 2;
    const int scol = (lane & 3) * 8;

    floatx4 acc[4][4] = {};

    for (int k0 = 0; k0 < K; k0 += 32) {
        #pragma unroll
        for (int c = 0; c < 2; ++c) {
            int ch = ch0 + c;
            const u16* ga = A + (size_t)(row0 + ch * 16 + srow) * lda + k0 + scol;
            __builtin_amdgcn_global_load_lds((AS1 void*)ga, (AS3 void*)&Alds[ch * 16][0], 16, 0, 0);
            const u16* gb = Bt + (size_t)(col0 + ch * 16 + srow) * ldb + k0 + scol;
            __builtin_amdgcn_global_load_lds((AS1 void*)gb, (AS3 void*)&Blds[ch * 16][0], 16, 0, 0);
        }
        __syncthreads();
        bf16x8 af[4], bfr[4];
        #pragma unroll
        for (int i = 0; i < 4; ++i) af[i] = *(const bf16x8*)&Alds[wm + i * 16 + l15][quad * 8];
        #pragma unroll
        for (int j = 0; j < 4; ++j) bfr[j] = *(const bf16x8*)&Blds[wn + j * 16 + l15][quad * 8];
        #pragma unroll
        for (int i = 0; i < 4; ++i)
            #pragma unroll
            for (int j = 0; j < 4; ++j)
                acc[i][j] = __builtin_amdgcn_mfma_f32_16x16x32_bf16(af[i], bfr[j], acc[i][j], 0, 0, 0);
        __syncthreads();
    }
    #pragma unroll
    for (int i = 0; i < 4; ++i) {
        #pragma unroll
        for (int r = 0; r < 4; ++r) {
            int row = row0 + wm + i * 16 + quad * 4 + r;
            size_t base = (size_t)row * ldc + col0 + wn + l15;
            #pragma unroll
            for (int j = 0; j < 4; ++j) C[base + j * 16] = f2bf(acc[i][j][r]);
        }
    }
}

// ---------- per-node attention scores (4 waves = 4 heads) ----------
__device__ __forceinline__ void score_node(int n, const float* hin,
    const float* wa1, const float* wa2, float* s_src, float* s_dst, int tid)
{
    const int hh = tid >> 6;
    const int lane = tid & 63;
    float h0 = hin[(long)n * DIM + lane];
    float h1 = hin[(long)n * DIM + 64 + lane];
    const float* w1 = wa1 + hh * DIM;
    const float* w2 = wa2 + hh * DIM;
    float p = h0 * w1[lane] + h1 * w1[64 + lane];
    float q = h0 * w2[lane] + h1 * w2[64 + lane];
    #pragma unroll
    for (int off = 32; off > 0; off >>= 1) {
        p += __shfl_down(p, off, 64);
        q += __shfl_down(q, off, 64);
    }
    if (lane == 0) { s_src[n * HEADS + hh] = p; s_dst[n * HEADS + hh] = q; }
}

// ---------- block-0 CSR scan: 256 threads x 64 nodes, two-pass ----------
__device__ __forceinline__ void scan_block(const int* deg, int* offs, int* cur,
                                           int tid, char* SMp)
{
    int* wsum = (int*)SMp;    // 4 ints
    const int4* d4 = (const int4*)deg;
    int tot = 0;
    if (tid < 250) {
        for (int i = 0; i < 16; ++i) {
            int4 v = d4[tid * 16 + i];
            tot += v.x + v.y + v.z + v.w;
        }
    }
    const int lane = tid & 63, w = tid >> 6;
    int x = tot;
    #pragma unroll
    for (int off = 1; off < 64; off <<= 1) {
        int t = __shfl_up(x, off, 64);
        if (lane >= off) x += t;
    }
    if (lane == 63) wsum[w] = x;
    __syncthreads();
    int pre = 0;
    for (int k = 0; k < w; ++k) pre += wsum[k];
    int run = pre + x - tot;   // exclusive prefix for this thread's chunk
    if (tid < 250) {
        for (int i = 0; i < 16; ++i) {
            int4 v = d4[tid * 16 + i];
            int4 o;
            o.x = run;
            o.y = run + v.x;
            o.z = o.y + v.y;
            o.w = o.z + v.z;
            ((int4*)offs)[tid * 16 + i] = o;
            ((int4*)cur)[tid * 16 + i] = o;
            run = o.w + v.w;
        }
        if (tid == 249) offs[N_NODES] = run;
    }
}

// ---------- per-node fused softmax + h-gather aggregation ----------
__device__ __forceinline__ void aggregate_node(int n,
    const float* s_src, const float* s_dst, const int* offs, const int* srcs,
    u16* xcat, char* SMp, int tid)
{
    float* attw  = (float*)SMp;             // [64][4] = 1024 B
    int*   ssrc  = (int*)(SMp + 1024);      // 256 B
    float* sdst4 = (float*)(SMp + 1280);    // 16 B
    float* redf  = (float*)(SMp + 1296);    // 1024 B
    float2* red2 = (float2*)(SMp + 2320);   // [256][4] = 8192 B

    const int start = offs[n];
    const int deg = offs[n + 1] - start;
    u32* xrow = (u32*)(xcat + (size_t)n * 640);
    if (deg == 0) { xrow[tid] = 0u; return; }

    if (tid < HEADS) sdst4[tid] = s_dst[n * HEADS + tid];
    __syncthreads();

    const int e4 = tid >> 6;
    const int dw = tid & 63;
    const int j  = tid >> 2;
    const int hh = tid & 3;
    const u32* hb = (const u32*)xcat;   // gather slice: row s dwords [s*320+256, s*320+320)

    float2 acc[4] = {{0.f,0.f},{0.f,0.f},{0.f,0.f},{0.f,0.f}};
    float dsum = 0.f;

    for (int cb = 0; cb < deg; cb += 64) {
        int clen = min(64, deg - cb);
        if (tid < clen) ssrc[tid] = srcs[start + cb + tid];
        __syncthreads();
        if (j < clen) {
            int s = ssrc[j];
            float e = s_src[s * HEADS + hh] + sdst4[hh];
            e = e > 0.f ? e : LRELU_ALPHA * e;
            float wv = __expf(e);
            attw[j * 4 + hh] = wv;
            dsum += wv;
        }
        __syncthreads();
        for (int jj = e4; jj < clen; jj += 4) {
            int s = ssrc[jj];
            u32 v = hb[s * 320 + 256 + dw];
            float lo = bflo(v), hi = bfhi(v);
            float4 wv = *(const float4*)(attw + jj * 4);
            acc[0].x = fmaf(wv.x, lo, acc[0].x); acc[0].y = fmaf(wv.x, hi, acc[0].y);
            acc[1].x = fmaf(wv.y, lo, acc[1].x); acc[1].y = fmaf(wv.y, hi, acc[1].y);
            acc[2].x = fmaf(wv.z, lo, acc[2].x); acc[2].y = fmaf(wv.z, hi, acc[2].y);
            acc[3].x = fmaf(wv.w, lo, acc[3].x); acc[3].y = fmaf(wv.w, hi, acc[3].y);
        }
        __syncthreads();
    }
    redf[tid] = dsum;
    __syncthreads();
    for (int off = 128; off >= 4; off >>= 1) {
        if (tid < off) redf[tid] += redf[tid + off];
        __syncthreads();
    }
    #pragma unroll
    for (int hq = 0; hq < 4; ++hq) red2[tid * 4 + hq] = acc[hq];
    __syncthreads();
    const int ho = tid >> 6, dwo = tid & 63;
    float invd = 1.f / redf[ho];
    float lo = 0.f, hi = 0.f;
    #pragma unroll
    for (int e = 0; e < 4; ++e) {
        float2 t = red2[(e * 64 + dwo) * 4 + ho];
        lo += t.x; hi += t.y;
    }
    xrow[tid] = (u32)f2bf(lo * invd) | ((u32)f2bf(hi * invd) << 16);
    __syncthreads();
}

// ================= the whole pipeline, one cooperative launch =================
__global__ __launch_bounds__(256, 2) void mega_kernel(
    const float* __restrict__ hin, const float* __restrict__ W, const float* __restrict__ a,
    const float* __restrict__ W_ih, const float* __restrict__ W_hh,
    const float* __restrict__ b_ih, const float* __restrict__ b_hh,
    const int* __restrict__ src, const int* __restrict__ dst,
    float* __restrict__ out,
    u16* __restrict__ xcat, u16* __restrict__ g,
    u16* __restrict__ Wihb, u16* __restrict__ Wb, u16* __restrict__ Wcat,
    float* __restrict__ wa1, float* __restrict__ wa2,
    float* __restrict__ s_src, float* __restrict__ s_dst,
    int* __restrict__ deg, int* __restrict__ offs, int* __restrict__ cur,
    int* __restrict__ ssort)
{
    __shared__ __align__(16) char SM[16384];
    cg::grid_group grid = cg::this_grid();
    const int tid = threadIdx.x;
    const int b = blockIdx.x;
    const int gt = b * NTHR + tid;

    // ---- PZ: deg zero | wa | weight casts | Wcat pack/zero | h->bf16 ----
    for (int i = gt; i < N_NODES + 1; i += GT_STRIDE) deg[i] = 0;
    if (gt < 512) {
        int h = gt >> 7;
        const float* wrow = W + (long)gt * DIM;
        const float* a1 = a + h * 2 * DIM;
        const float* a2 = a1 + DIM;
        float s1 = 0.f, s2 = 0.f;
        for (int e = 0; e < DIM; ++e) {
            float w = wrow[e];
            s1 = fmaf(w, a1[e], s1);
            s2 = fmaf(w, a2[e], s2);
        }
        wa1[gt] = s1;
        wa2[gt] = s2;
    }
    for (int i = gt; i < 384 * 512; i += GT_STRIDE) Wihb[i] = f2bf(W_ih[i]);
    if (gt < HEADS * DIM * DIM) Wb[gt] = f2bf(W[gt]);
    if (gt < 512 * 128) {
        int j = gt >> 7, e = gt & 127;
        u16 val;
        if (j < 256)      val = f2bf(W_hh[j * 128 + e]);
        else if (j < 384) val = 0;
        else              val = f2bf(W_hh[(j - 128) * 128 + e]);
        Wcat[(size_t)j * 640 + 512 + e] = val;
    }
    if (gt < 128 * 512) {
        int j = 384 + (gt >> 9), c = gt & 511;
        Wcat[(size_t)j * 640 + c] = 0;
    }
    {
        const float2* h2 = (const float2*)hin;
        u32* xc32 = (u32*)xcat;
        for (int p = gt; p < N_NODES * 64; p += GT_STRIDE) {
            int n = p >> 6, d = p & 63;
            float2 hv = h2[p];
            xc32[n * 320 + 256 + d] = (u32)f2bf(hv.x) | ((u32)f2bf(hv.y) << 16);
        }
    }
    grid.sync();

    // ---- P1: deg histogram ----
    for (int e = gt; e < E_EDGES; e += GT_STRIDE) atomicAdd(&deg[dst[e]], 1);
    grid.sync();

    // ---- P2: scan (block 0) || Mt mini-GEMM (blocks 1..12) || scores (13..511) ----
    if (b == 0) {
        scan_block(deg, offs, cur, tid, SM);
    } else if (b <= 12) {
        int q = b - 1, y = q % 3, z = q / 3;
        // Mt: Wcat[j][z*128+d] = sum_e W_ih[j][z*128+e] * W[z][d][e]
        gemm_tile(Wihb + z * 128, Wb + (size_t)z * 16384, Wcat + z * 128,
                  128, 512, 128, 640, y * 128, 0, SM, tid);
    } else {
        for (int n = b - 13; n < N_NODES; n += NBLK - 13)
            score_node(n, hin, wa1, wa2, s_src, s_dst, tid);
    }
    grid.sync();

    // ---- P3: scatter edges into CSR ----
    for (int e = gt; e < E_EDGES; e += GT_STRIDE) {
        int pos = atomicAdd(&cur[dst[e]], 1);
        ssort[pos] = src[e];
    }
    grid.sync();

    // ---- P4: fused softmax + gather aggregation ----
    for (int n = b; n < N_NODES; n += NBLK)
        aggregate_node(n, s_src, s_dst, offs, ssort, xcat, SM, tid);
    grid.sync();

    // ---- P5: main GEMM g = xcat(16000x640) @ Wcat(512x640)^T ----
    if (b < 500)
        gemm_tile(xcat, Wcat, g, 640, 640, 640, 512, (b >> 2) * 128, (b & 3) * 128, SM, tid);
    grid.sync();

    // ---- P6: GRU elementwise ----
    for (int idx = gt; idx < N_NODES * DIM; idx += GT_STRIDE) {
        int n = idx >> 7, d = idx & 127;
        const u16* gr = g + (size_t)n * 512;
        float A  = bfs(gr[d])       + b_ih[d]       + b_hh[d];
        float B  = bfs(gr[128 + d]) + b_ih[128 + d] + b_hh[128 + d];
        float Cn = bfs(gr[256 + d]) + b_ih[256 + d];
        float Dn = bfs(gr[384 + d]) + b_hh[256 + d];
        float r = 1.f / (1.f + __expf(-A));
        float z = 1.f / (1.f + __expf(-B));
        float pre = Cn + r * Dn;
        float e2 = __expf(2.f * pre);
        float nv = (e2 - 1.f) / (e2 + 1.f);
        out[idx] = (1.f - z) * nv + z * hin[idx];
    }
}

extern "C" void kernel_launch(void* const* d_in, const int* in_sizes, int n_in,
                              void* d_out, int out_size, void* d_ws, size_t ws_size,
                              hipStream_t stream)
{
    const float* h    = (const float*)d_in[0];
    const float* W    = (const float*)d_in[1];
    const float* a    = (const float*)d_in[2];
    const float* W_ih = (const float*)d_in[3];
    const float* W_hh = (const float*)d_in[4];
    const float* b_ih = (const float*)d_in[5];
    const float* b_hh = (const float*)d_in[6];
    const int*   src  = (const int*)d_in[7];
    const int*   dst  = (const int*)d_in[8];
    float* out = (float*)d_out;

    char* ws = (char*)d_ws;
    size_t off = 0;
    auto alloc = [&](size_t bytes) { void* p = ws + off; off += (bytes + 255) & ~(size_t)255; return p; };

    u16*   xcat = (u16*)alloc((size_t)N_NODES * 640 * 2);   // [hagg(512) | hbf(128)]
    u16*   g    = (u16*)alloc((size_t)N_NODES * 512 * 2);   // [r_sum | z_sum | i_n | h_n]
    u16*   Wihb = (u16*)alloc(384 * 512 * 2);
    u16*   Wb   = (u16*)alloc(HEADS * 128 * 128 * 2);
    u16*   Wcat = (u16*)alloc(512 * 640 * 2);
    float* wa1  = (float*)alloc(512 * 4);
    float* wa2  = (float*)alloc(512 * 4);
    float* s_src = (float*)alloc((size_t)N_NODES * HEADS * 4);
    float* s_dst = (float*)alloc((size_t)N_NODES * HEADS * 4);
    int*   deg  = (int*)alloc((N_NODES + 1) * 4);
    int*   offs = (int*)alloc((N_NODES + 1) * 4);
    int*   cur  = (int*)alloc(N_NODES * 4);
    int*   ssort = (int*)alloc((size_t)E_EDGES * 4);

    void* args[] = {
        (void*)&h, (void*)&W, (void*)&a, (void*)&W_ih, (void*)&W_hh,
        (void*)&b_ih, (void*)&b_hh, (void*)&src, (void*)&dst, (void*)&out,
        (void*)&xcat, (void*)&g, (void*)&Wihb, (void*)&Wb, (void*)&Wcat,
        (void*)&wa1, (void*)&wa2, (void*)&s_src, (void*)&s_dst,
        (void*)&deg, (void*)&offs, (void*)&cur, (void*)&ssort
    };
    hipLaunchCooperativeKernel((const void*)mega_kernel, dim3(NBLK), dim3(NTHR),
                               args, 0, stream);
}

// Round 6
// 166.266 us; speedup vs baseline: 3.7663x; 3.7663x over previous
//
#include <hip/hip_runtime.h>
#include <math.h>

#define N_NODES 16000
#define E_EDGES 256000
#define DIM 128
#define HEADS 4
#define LRELU_ALPHA 0.2f

typedef unsigned short u16;
typedef unsigned int u32;
typedef short bf16x8 __attribute__((ext_vector_type(8)));
typedef float floatx4 __attribute__((ext_vector_type(4)));

#define AS1 __attribute__((address_space(1)))
#define AS3 __attribute__((address_space(3)))

__device__ __forceinline__ u16 f2bf(float f) {
    u32 u = __float_as_uint(f);
    u32 r = (u + 0x7fffu + ((u >> 16) & 1u)) >> 16;   // RNE
    return (u16)r;
}
__device__ __forceinline__ float bflo(u32 v) { return __uint_as_float(v << 16); }
__device__ __forceinline__ float bfhi(u32 v) { return __uint_as_float(v & 0xffff0000u); }
__device__ __forceinline__ u32 pack2(float lo, float hi) {
    return (u32)f2bf(lo) | ((u32)f2bf(hi) << 16);
}

// ---------- L1: deg zero + wa ----------
__global__ __launch_bounds__(256) void init_kernel(
    const float* __restrict__ W, const float* __restrict__ a,
    float* __restrict__ wa1, float* __restrict__ wa2, int* __restrict__ deg)
{
    int t = blockIdx.x * blockDim.x + threadIdx.x;
    if (t <= N_NODES) deg[t] = 0;
    if (t < HEADS * DIM) {
        int h = t >> 7;
        const float* wrow = W + (long)t * DIM;
        const float* a1 = a + h * 2 * DIM;
        const float* a2 = a1 + DIM;
        float s1 = 0.f, s2 = 0.f;
        for (int e = 0; e < DIM; ++e) {
            float w = wrow[e];
            s1 = fmaf(w, a1[e], s1);
            s2 = fmaf(w, a2[e], s2);
        }
        wa1[t] = s1;
        wa2[t] = s2;
    }
}

// ---------- L2: scores+hbf | deg hist | weight casts | Wcat pack ----------
// blocks [0,16000): scores; [16000,17000): hist; [17000,17768): casts; [17768,18280): pack
__global__ __launch_bounds__(256) void prep_kernel(
    const float* __restrict__ hin, const float* __restrict__ wa1, const float* __restrict__ wa2,
    const float* __restrict__ W_ih, const float* __restrict__ W, const float* __restrict__ W_hh,
    const int* __restrict__ dst,
    float* __restrict__ s_src, float* __restrict__ s_dst,
    u16* __restrict__ xcat, u16* __restrict__ Wihb, u16* __restrict__ Wb,
    u16* __restrict__ Wcat, int* __restrict__ deg)
{
    const int b = blockIdx.x;
    const int tid = threadIdx.x;
    if (b < N_NODES) {
        const int n = b;
        const int hh = tid >> 6;
        const int lane = tid & 63;
        float h0 = hin[(long)n * DIM + lane];
        float h1 = hin[(long)n * DIM + 64 + lane];
        if (hh == 0) {
            xcat[(size_t)n * 640 + 512 + lane] = f2bf(h0);
            xcat[(size_t)n * 640 + 576 + lane] = f2bf(h1);
        }
        const float* w1 = wa1 + hh * DIM;
        const float* w2 = wa2 + hh * DIM;
        float p = h0 * w1[lane] + h1 * w1[64 + lane];
        float q = h0 * w2[lane] + h1 * w2[64 + lane];
        #pragma unroll
        for (int off = 32; off > 0; off >>= 1) {
            p += __shfl_down(p, off, 64);
            q += __shfl_down(q, off, 64);
        }
        if (lane == 0) { s_src[n * HEADS + hh] = p; s_dst[n * HEADS + hh] = q; }
    } else if (b < N_NODES + 1000) {
        int e = (b - N_NODES) * 256 + tid;
        atomicAdd(&deg[dst[e]], 1);
    } else if (b < N_NODES + 1768) {
        int i = (b - N_NODES - 1000) * 256 + tid;   // [0, 196608)
        Wihb[i] = f2bf(W_ih[i]);
        if (i < HEADS * DIM * DIM) Wb[i] = f2bf(W[i]);
    } else {
        int t = (b - N_NODES - 1768) * 256 + tid;   // [0, 131072)
        if (t < 65536) {
            int j = t >> 7, e = t & 127;
            u16 val;
            if (j < 256)      val = f2bf(W_hh[j * 128 + e]);
            else if (j < 384) val = 0;
            else              val = f2bf(W_hh[(j - 128) * 128 + e]);
            Wcat[(size_t)j * 640 + 512 + e] = val;
        } else {
            int t2 = t - 65536;
            int j = 384 + (t2 >> 9), c = t2 & 511;
            Wcat[(size_t)j * 640 + c] = 0;
        }
    }
}

// ---------- L3: single-pass scan, 1024 threads x 16 elems ----------
__global__ __launch_bounds__(1024) void scan_kernel(const int* __restrict__ deg,
    int* __restrict__ offsets, int* __restrict__ cursor)
{
    __shared__ int wsum[16];
    const int tid = threadIdx.x;
    const int lane = tid & 63;
    const int w = tid >> 6;
    const int4* d4 = (const int4*)deg;
    int v[16];
    int tot = 0;
    #pragma unroll
    for (int i = 0; i < 4; ++i) {
        int i4 = tid * 4 + i;
        int4 vv = (i4 < N_NODES / 4) ? d4[i4] : int4{0, 0, 0, 0};
        v[i * 4 + 0] = vv.x; v[i * 4 + 1] = vv.y; v[i * 4 + 2] = vv.z; v[i * 4 + 3] = vv.w;
        tot += vv.x + vv.y + vv.z + vv.w;
    }
    int x = tot;
    #pragma unroll
    for (int off = 1; off < 64; off <<= 1) {
        int t = __shfl_up(x, off, 64);
        if (lane >= off) x += t;
    }
    if (lane == 63) wsum[w] = x;
    __syncthreads();
    if (w == 0) {
        int s = (lane < 16) ? wsum[lane] : 0;
        #pragma unroll
        for (int off = 1; off < 16; off <<= 1) {
            int t = __shfl_up(s, off, 64);
            if (lane >= off) s += t;
        }
        if (lane < 16) wsum[lane] = s;
    }
    __syncthreads();
    int excl = x - tot + ((w == 0) ? 0 : wsum[w - 1]);
    #pragma unroll
    for (int i = 0; i < 4; ++i) {
        int i4 = tid * 4 + i;
        if (i4 < N_NODES / 4) {
            int4 o;
            o.x = excl;
            o.y = excl + v[i * 4];
            o.z = o.y + v[i * 4 + 1];
            o.w = o.z + v[i * 4 + 2];
            ((int4*)offsets)[i4] = o;
            ((int4*)cursor)[i4] = o;
            excl = o.w + v[i * 4 + 3];
        }
    }
    if (tid == 1023) offsets[N_NODES] = excl;
}

// ---------- shared 128x128 bf16 MFMA TN tile ----------
__device__ __forceinline__ void gemm_tile(const u16* A, const u16* Bt, u16* C,
    int K, int lda, int ldb, int ldc, int row0, int col0, char* SMp, int tid)
{
    u16 (*Alds)[32] = (u16(*)[32])SMp;
    u16 (*Blds)[32] = (u16(*)[32])(SMp + 8192);
    const int wave = tid >> 6;
    const int lane = tid & 63;
    const int quad = lane >> 4;
    const int l15  = lane & 15;
    const int wm = (wave >> 1) * 64;
    const int wn = (wave & 1) * 64;
    const int ch0 = wave * 2;
    const int srow = lane >> 2;
    const int scol = (lane & 3) * 8;

    floatx4 acc[4][4] = {};

    for (int k0 = 0; k0 < K; k0 += 32) {
        #pragma unroll
        for (int c = 0; c < 2; ++c) {
            int ch = ch0 + c;
            const u16* ga = A + (size_t)(row0 + ch * 16 + srow) * lda + k0 + scol;
            __builtin_amdgcn_global_load_lds((AS1 void*)ga, (AS3 void*)&Alds[ch * 16][0], 16, 0, 0);
            const u16* gb = Bt + (size_t)(col0 + ch * 16 + srow) * ldb + k0 + scol;
            __builtin_amdgcn_global_load_lds((AS1 void*)gb, (AS3 void*)&Blds[ch * 16][0], 16, 0, 0);
        }
        __syncthreads();
        bf16x8 af[4], bfr[4];
        #pragma unroll
        for (int i = 0; i < 4; ++i) af[i] = *(const bf16x8*)&Alds[wm + i * 16 + l15][quad * 8];
        #pragma unroll
        for (int j = 0; j < 4; ++j) bfr[j] = *(const bf16x8*)&Blds[wn + j * 16 + l15][quad * 8];
        #pragma unroll
        for (int i = 0; i < 4; ++i)
            #pragma unroll
            for (int j = 0; j < 4; ++j)
                acc[i][j] = __builtin_amdgcn_mfma_f32_16x16x32_bf16(af[i], bfr[j], acc[i][j], 0, 0, 0);
        __syncthreads();
    }
    #pragma unroll
    for (int i = 0; i < 4; ++i) {
        #pragma unroll
        for (int r = 0; r < 4; ++r) {
            int row = row0 + wm + i * 16 + quad * 4 + r;
            size_t base = (size_t)row * ldc + col0 + wn + l15;
            #pragma unroll
            for (int j = 0; j < 4; ++j) C[base + j * 16] = f2bf(acc[i][j][r]);
        }
    }
}

// ---------- L4: scatter edges | Mt mini-GEMM (blocks 0..11) ----------
__global__ __launch_bounds__(256) void scatter_mt_kernel(
    const int* __restrict__ src, const int* __restrict__ dst,
    int* __restrict__ cursor, int* __restrict__ ssorted,
    const u16* __restrict__ Wihb, const u16* __restrict__ Wb, u16* __restrict__ Wcat)
{
    __shared__ __align__(16) char SM[16384];
    const int b = blockIdx.x;
    const int tid = threadIdx.x;
    if (b < 12) {
        int y = b % 3, z = b / 3;
        // Wcat[j][z*128+d] = sum_e W_ih[j][z*128+e] * W[z][d][e]
        gemm_tile(Wihb + z * 128, Wb + (size_t)z * 16384, Wcat + z * 128,
                  128, 512, 128, 640, y * 128, 0, SM, tid);
    } else {
        int e = (b - 12) * 256 + tid;
        int pos = atomicAdd(&cursor[dst[e]], 1);
        ssorted[pos] = src[e];
    }
}

// ---------- L5: wave-per-node fused softmax + gather aggregation ----------
// Lane owns one dword (2 dims) of the gathered h row for ALL 4 heads.
// No LDS, no __syncthreads — all broadcast via shuffles.
__global__ __launch_bounds__(256) void aggregate_kernel(
    const float* __restrict__ s_src, const float* __restrict__ s_dst,
    const int* __restrict__ offs, const int* __restrict__ srcs,
    u16* __restrict__ xcat)
{
    const int tid = threadIdx.x;
    const int lane = tid & 63;
    const int n = blockIdx.x * 4 + (tid >> 6);
    const int start = offs[n];
    const int deg = offs[n + 1] - start;
    u32* xrow = (u32*)(xcat + (size_t)n * 640);
    if (deg == 0) {
        #pragma unroll
        for (int h = 0; h < 4; ++h) xrow[h * 64 + lane] = 0u;
        return;
    }
    const u32* hb = (const u32*)xcat;   // gather slice: row s dwords [s*320+256, s*320+320)
    const float sd = s_dst[n * HEADS + (lane & 3)];
    const int j16 = lane >> 2;
    const int hh  = lane & 3;

    float2 acc[4] = {{0.f,0.f},{0.f,0.f},{0.f,0.f},{0.f,0.f}};
    float dsum[4] = {0.f, 0.f, 0.f, 0.f};

    for (int cb = 0; cb < deg; cb += 16) {
        const int clen = min(16, deg - cb);
        int sv = 0;
        if (lane < clen) sv = srcs[start + cb + lane];
        // lanes (j,h): weight for edge j, head h
        float wv = 0.f;
        if (j16 < clen) {
            int s = __shfl(sv, j16, 64);
            float e = s_src[s * HEADS + hh] + sd;
            e = e > 0.f ? e : LRELU_ALPHA * e;
            wv = __expf(e);
        }
        int e = 0;
        for (; e + 4 <= clen; e += 4) {
            u32 vs[4];
            #pragma unroll
            for (int k = 0; k < 4; ++k) {
                int s = __shfl(sv, e + k, 64);
                vs[k] = hb[s * 320 + 256 + lane];
            }
            #pragma unroll
            for (int k = 0; k < 4; ++k) {
                float lo = bflo(vs[k]), hi = bfhi(vs[k]);
                #pragma unroll
                for (int h = 0; h < 4; ++h) {
                    float w = __shfl(wv, (e + k) * 4 + h, 64);
                    acc[h].x = fmaf(w, lo, acc[h].x);
                    acc[h].y = fmaf(w, hi, acc[h].y);
                    dsum[h] += w;
                }
            }
        }
        for (; e < clen; ++e) {
            int s = __shfl(sv, e, 64);
            u32 v = hb[s * 320 + 256 + lane];
            float lo = bflo(v), hi = bfhi(v);
            #pragma unroll
            for (int h = 0; h < 4; ++h) {
                float w = __shfl(wv, e * 4 + h, 64);
                acc[h].x = fmaf(w, lo, acc[h].x);
                acc[h].y = fmaf(w, hi, acc[h].y);
                dsum[h] += w;
            }
        }
    }
    #pragma unroll
    for (int h = 0; h < 4; ++h) {
        float invd = 1.f / dsum[h];
        xrow[h * 64 + lane] = pack2(acc[h].x * invd, acc[h].y * invd);
    }
}

// ---------- L6: main GEMM g = xcat(16000x640) @ Wcat(512x640)^T ----------
__global__ __launch_bounds__(256) void gemm_main_kernel(
    const u16* __restrict__ xcat, const u16* __restrict__ Wcat, u16* __restrict__ g)
{
    __shared__ __align__(16) char SM[16384];
    gemm_tile(xcat, Wcat, g, 640, 640, 640, 512,
              blockIdx.y * 128, blockIdx.x * 128, SM, threadIdx.x);
}

// ---------- L7: GRU elementwise, 2 dims/thread ----------
__global__ __launch_bounds__(256) void gru_kernel(const u32* __restrict__ g32,
    const float* __restrict__ b_ih, const float* __restrict__ b_hh,
    const float* __restrict__ hin, float* __restrict__ out)
{
    int p = blockIdx.x * blockDim.x + threadIdx.x;   // dword id over N*64
    if (p >= N_NODES * 64) return;
    int n = p >> 6, d2 = p & 63;
    const u32* gr = g32 + (size_t)n * 256;
    u32 vr = gr[d2], vz = gr[64 + d2], vi = gr[128 + d2], vh = gr[192 + d2];
    const float2* bi2 = (const float2*)b_ih;
    const float2* bh2 = (const float2*)b_hh;
    float2 bir = bi2[d2],      bhr = bh2[d2];
    float2 biz = bi2[64 + d2], bhz = bh2[64 + d2];
    float2 bin = bi2[128 + d2], bhn = bh2[128 + d2];
    float2 hv = ((const float2*)hin)[p];
    float2 o;
    {
        float A = bflo(vr) + bir.x + bhr.x;
        float B = bflo(vz) + biz.x + bhz.x;
        float Cn = bflo(vi) + bin.x;
        float Dn = bflo(vh) + bhn.x;
        float r = 1.f / (1.f + __expf(-A));
        float z = 1.f / (1.f + __expf(-B));
        float e2 = __expf(2.f * (Cn + r * Dn));
        float nv = (e2 - 1.f) / (e2 + 1.f);
        o.x = (1.f - z) * nv + z * hv.x;
    }
    {
        float A = bfhi(vr) + bir.y + bhr.y;
        float B = bfhi(vz) + biz.y + bhz.y;
        float Cn = bfhi(vi) + bin.y;
        float Dn = bfhi(vh) + bhn.y;
        float r = 1.f / (1.f + __expf(-A));
        float z = 1.f / (1.f + __expf(-B));
        float e2 = __expf(2.f * (Cn + r * Dn));
        float nv = (e2 - 1.f) / (e2 + 1.f);
        o.y = (1.f - z) * nv + z * hv.y;
    }
    ((float2*)out)[p] = o;
}

extern "C" void kernel_launch(void* const* d_in, const int* in_sizes, int n_in,
                              void* d_out, int out_size, void* d_ws, size_t ws_size,
                              hipStream_t stream)
{
    const float* h    = (const float*)d_in[0];
    const float* W    = (const float*)d_in[1];
    const float* a    = (const float*)d_in[2];
    const float* W_ih = (const float*)d_in[3];
    const float* W_hh = (const float*)d_in[4];
    const float* b_ih = (const float*)d_in[5];
    const float* b_hh = (const float*)d_in[6];
    const int*   src  = (const int*)d_in[7];
    const int*   dst  = (const int*)d_in[8];
    float* out = (float*)d_out;

    char* ws = (char*)d_ws;
    size_t off = 0;
    auto alloc = [&](size_t bytes) { void* p = ws + off; off += (bytes + 255) & ~(size_t)255; return p; };

    u16*   xcat = (u16*)alloc((size_t)N_NODES * 640 * 2);   // [hagg(512) | hbf(128)]
    u16*   g    = (u16*)alloc((size_t)N_NODES * 512 * 2);   // [r_sum | z_sum | i_n | h_n]
    u16*   Wihb = (u16*)alloc(384 * 512 * 2);
    u16*   Wb   = (u16*)alloc(HEADS * 128 * 128 * 2);
    u16*   Wcat = (u16*)alloc(512 * 640 * 2);
    float* wa1  = (float*)alloc(512 * 4);
    float* wa2  = (float*)alloc(512 * 4);
    float* s_src = (float*)alloc((size_t)N_NODES * HEADS * 4);
    float* s_dst = (float*)alloc((size_t)N_NODES * HEADS * 4);
    int*   deg  = (int*)alloc((N_NODES + 1) * 4);
    int*   offs = (int*)alloc((N_NODES + 1) * 4);
    int*   cur  = (int*)alloc(N_NODES * 4);
    int*   ssort = (int*)alloc((size_t)E_EDGES * 4);

    init_kernel<<<64, 256, 0, stream>>>(W, a, wa1, wa2, deg);

    prep_kernel<<<N_NODES + 1768 + 512, 256, 0, stream>>>(
        h, wa1, wa2, W_ih, W, W_hh, dst, s_src, s_dst, xcat, Wihb, Wb, Wcat, deg);

    scan_kernel<<<1, 1024, 0, stream>>>(deg, offs, cur);

    scatter_mt_kernel<<<1012, 256, 0, stream>>>(src, dst, cur, ssort, Wihb, Wb, Wcat);

    aggregate_kernel<<<N_NODES / 4, 256, 0, stream>>>(s_src, s_dst, offs, ssort, xcat);

    gemm_main_kernel<<<dim3(4, 125), 256, 0, stream>>>(xcat, Wcat, g);

    gru_kernel<<<(N_NODES * 64 + 255) / 256, 256, 0, stream>>>(
        (const u32*)g, b_ih, b_hh, h, out);
}